// Round 2
// baseline (1570.392 us; speedup 1.0000x reference)
//
#include <hip/hip_runtime.h>

#define NN 100000
#define NE 1200000
#define NF 128
#define NH 64
#define NC 16

// ---------------- fc0: h0 = x @ fc0_w + fc0_b  (pre-ReLU stored) ----------------
__global__ __launch_bounds__(256) void fc0_kernel(const float* __restrict__ x,
                                                  const float* __restrict__ w,
                                                  const float* __restrict__ b,
                                                  float* __restrict__ h0,
                                                  int nwaves) {
    __shared__ float wl[NF * NH];  // 32 KB
    {
        const float4* w4 = (const float4*)w;
        float4* wl4 = (float4*)wl;
        for (int i = threadIdx.x; i < NF * NH / 4; i += 256) wl4[i] = w4[i];
    }
    __syncthreads();
    const int lane = threadIdx.x & 63;
    const int wid = (blockIdx.x * 256 + threadIdx.x) >> 6;
    const float bias = b[lane];
    for (int n = wid; n < NN; n += nwaves) {
        float a0 = x[n * NF + lane];
        float a1 = x[n * NF + 64 + lane];
        float acc = bias;
#pragma unroll
        for (int k = 0; k < 64; ++k) {
            float va = __shfl(a0, k);
            acc = fmaf(va, wl[k * NH + lane], acc);
        }
#pragma unroll
        for (int k = 0; k < 64; ++k) {
            float va = __shfl(a1, k);
            acc = fmaf(va, wl[(64 + k) * NH + lane], acc);
        }
        h0[n * NH + lane] = acc;
    }
}

// ------------- conv layer matmul (fused with accumulator init) -------------
// xw[n]  = 0.9 * (relu(in[n]) @ W)       (in-place safe: in may alias xw)
// acc[n] = 0.1 * h0[n] + b
__global__ __launch_bounds__(256) void conv_kernel(const float* __restrict__ in,
                                                   float* __restrict__ xw,
                                                   const float* __restrict__ h0,
                                                   float* __restrict__ acc,
                                                   const float* __restrict__ w,
                                                   const float* __restrict__ b,
                                                   int nwaves) {
    __shared__ float wl[NH * NH];  // 16 KB
    {
        const float4* w4 = (const float4*)w;
        float4* wl4 = (float4*)wl;
        for (int i = threadIdx.x; i < NH * NH / 4; i += 256) wl4[i] = w4[i];
    }
    __syncthreads();
    const int lane = threadIdx.x & 63;
    const int wid = (blockIdx.x * 256 + threadIdx.x) >> 6;
    const float bias = b[lane];
    for (int n = wid; n < NN; n += nwaves) {
        float a = in[n * NH + lane];
        a = fmaxf(a, 0.0f);  // ReLU on load
        float h = h0[n * NH + lane];
        float s = 0.0f;
#pragma unroll
        for (int k = 0; k < 64; ++k) {
            float va = __shfl(a, k);
            s = fmaf(va, wl[k * NH + lane], s);
        }
        xw[n * NH + lane] = 0.9f * s;              // fold (1-ALPHA)
        acc[n * NH + lane] = fmaf(0.1f, h, bias);  // 0.1*h0 + conv_b
    }
}

// ---------------- SpMM: acc[row] += val * xw[col], one wave per edge ----------------
__global__ __launch_bounds__(256) void spmm_kernel(const int* __restrict__ rows,
                                                   const int* __restrict__ cols,
                                                   const float* __restrict__ vals,
                                                   const float* __restrict__ xw,
                                                   float* __restrict__ acc,
                                                   int nwaves) {
    const int lane = threadIdx.x & 63;
    const int wid = (blockIdx.x * 256 + threadIdx.x) >> 6;
    for (int e = wid; e < NE; e += nwaves) {
        int r = rows[e];
        int c = cols[e];
        float v = vals[e];
        float msg = v * xw[c * NH + lane];
        unsafeAtomicAdd(&acc[r * NH + lane], msg);  // global_atomic_add_f32
    }
}

// ---------------- fc1: out = relu(in) @ fc1_w + fc1_b ----------------
__global__ __launch_bounds__(256) void fc1_kernel(const float* __restrict__ in,
                                                  const float* __restrict__ w,
                                                  const float* __restrict__ b,
                                                  float* __restrict__ out,
                                                  int nwaves) {
    __shared__ float wl[NH * NC];  // 4 KB
    for (int i = threadIdx.x; i < NH * NC; i += 256) wl[i] = w[i];
    __syncthreads();
    const int lane = threadIdx.x & 63;
    const int wid = (blockIdx.x * 256 + threadIdx.x) >> 6;
    const int c = lane & 15;
    const int r = lane >> 4;
    const int src_base = lane & 48;  // r*16
    const float bias = b[c];
    for (int g = wid; g < NN / 4; g += nwaves) {
        int row = g * 4 + r;
        float a0 = fmaxf(in[row * NH + c], 0.0f);
        float a1 = fmaxf(in[row * NH + 16 + c], 0.0f);
        float a2 = fmaxf(in[row * NH + 32 + c], 0.0f);
        float a3 = fmaxf(in[row * NH + 48 + c], 0.0f);
        float s = bias;
#pragma unroll
        for (int k = 0; k < 16; ++k) s = fmaf(__shfl(a0, src_base + k), wl[k * NC + c], s);
#pragma unroll
        for (int k = 0; k < 16; ++k) s = fmaf(__shfl(a1, src_base + k), wl[(16 + k) * NC + c], s);
#pragma unroll
        for (int k = 0; k < 16; ++k) s = fmaf(__shfl(a2, src_base + k), wl[(32 + k) * NC + c], s);
#pragma unroll
        for (int k = 0; k < 16; ++k) s = fmaf(__shfl(a3, src_base + k), wl[(48 + k) * NC + c], s);
        out[row * NC + c] = s;
    }
}

extern "C" void kernel_launch(void* const* d_in, const int* in_sizes, int n_in,
                              void* d_out, int out_size, void* d_ws, size_t ws_size,
                              hipStream_t stream) {
    const float* x = (const float*)d_in[0];
    const int* rows = (const int*)d_in[1];
    const int* cols = (const int*)d_in[2];
    const float* vals = (const float*)d_in[3];
    const float* fc0_w = (const float*)d_in[4];
    const float* fc0_b = (const float*)d_in[5];
    const float* conv_w = (const float*)d_in[6];
    const float* conv_b = (const float*)d_in[7];
    const float* fc1_w = (const float*)d_in[8];
    const float* fc1_b = (const float*)d_in[9];
    float* out = (float*)d_out;

    float* h0 = (float*)d_ws;                      // [NN*NH]
    float* bufA = h0 + (size_t)NN * NH;            // [NN*NH]
    float* bufB = bufA + (size_t)NN * NH;          // [NN*NH]

    const int blocks = 2048;
    const int nwaves = blocks * 4;

    fc0_kernel<<<blocks, 256, 0, stream>>>(x, fc0_w, fc0_b, h0, nwaves);

    // layer ping-pong: L1 h0->A(xw),B(acc); L2 B->B,A; L3 A->A,B; L4 B->B,A
    const float* in_buf = h0;
    for (int i = 0; i < 4; ++i) {
        float* xw;
        float* acc;
        if (i == 0) { xw = bufA; acc = bufB; }
        else if (i == 1) { xw = bufB; acc = bufA; }
        else if (i == 2) { xw = bufA; acc = bufB; }
        else { xw = bufB; acc = bufA; }
        conv_kernel<<<blocks, 256, 0, stream>>>(in_buf, xw, h0, acc,
                                                conv_w + i * NH * NH, conv_b + i * NH, nwaves);
        spmm_kernel<<<blocks, 256, 0, stream>>>(rows, cols, vals, xw, acc, nwaves);
        in_buf = acc;
    }

    fc1_kernel<<<1024, 256, 0, stream>>>(in_buf, fc1_w, fc1_b, out, 1024 * 4);
}

// Round 3
// 989.149 us; speedup vs baseline: 1.5876x; 1.5876x over previous
//
#include <hip/hip_runtime.h>
#include <hip/hip_bf16.h>

#define NN 100000
#define NE 1200000
#define NF 128
#define NH 64
#define NC 16
#define NB_SCAN 391  // ceil(NN/256)

// ---------------- CSR build ----------------
__global__ __launch_bounds__(256) void zero_deg_kernel(int* __restrict__ deg) {
    int i = blockIdx.x * 256 + threadIdx.x;
    if (i < NN) deg[i] = 0;
}

__global__ __launch_bounds__(256) void hist_kernel(const int* __restrict__ rows,
                                                   int* __restrict__ deg, int nthreads) {
    for (int e = blockIdx.x * 256 + threadIdx.x; e < NE; e += nthreads)
        atomicAdd(&deg[rows[e]], 1);
}

// block-local exclusive scan; rs[i] = exclusive-within-block, blk[b] = block total
__global__ __launch_bounds__(256) void scan1_kernel(const int* __restrict__ deg,
                                                    int* __restrict__ rs,
                                                    int* __restrict__ blk) {
    __shared__ int sm[256];
    const int tid = threadIdx.x;
    const int i = blockIdx.x * 256 + tid;
    int v = (i < NN) ? deg[i] : 0;
    sm[tid] = v;
    __syncthreads();
#pragma unroll
    for (int off = 1; off < 256; off <<= 1) {
        int t = (tid >= off) ? sm[tid - off] : 0;
        __syncthreads();
        sm[tid] += t;
        __syncthreads();
    }
    if (i < NN) rs[i] = sm[tid] - v;  // exclusive
    if (tid == 255) blk[blockIdx.x] = sm[255];
}

__global__ __launch_bounds__(512) void scan2_kernel(const int* __restrict__ blk,
                                                    int* __restrict__ blk_off) {
    __shared__ int sm[512];
    const int tid = threadIdx.x;
    int v = (tid < NB_SCAN) ? blk[tid] : 0;
    sm[tid] = v;
    __syncthreads();
#pragma unroll
    for (int off = 1; off < 512; off <<= 1) {
        int t = (tid >= off) ? sm[tid - off] : 0;
        __syncthreads();
        sm[tid] += t;
        __syncthreads();
    }
    if (tid < NB_SCAN) blk_off[tid] = sm[tid] - v;  // exclusive
}

__global__ __launch_bounds__(256) void scan3_kernel(int* __restrict__ rs,
                                                    const int* __restrict__ blk_off,
                                                    int* __restrict__ cursor) {
    int i = blockIdx.x * 256 + threadIdx.x;
    if (i < NN) {
        int v = rs[i] + blk_off[i >> 8];
        rs[i] = v;
        cursor[i] = v;
    }
    if (i == 0) rs[NN] = NE;
}

__global__ __launch_bounds__(256) void scatter_kernel(const int* __restrict__ rows,
                                                      const int* __restrict__ cols,
                                                      const float* __restrict__ vals,
                                                      int* __restrict__ cursor,
                                                      int2* __restrict__ packed, int nthreads) {
    for (int e = blockIdx.x * 256 + threadIdx.x; e < NE; e += nthreads) {
        int r = rows[e];
        int pos = atomicAdd(&cursor[r], 1);
        packed[pos] = make_int2(cols[e], __float_as_int(vals[e]));
    }
}

// ---------------- fc0: h0 = x @ fc0_w + b (pre-ReLU, stored bf16) ----------------
__global__ __launch_bounds__(256, 2) void fc0_kernel(const float* __restrict__ x,
                                                     const float* __restrict__ w,
                                                     const float* __restrict__ b,
                                                     __hip_bfloat16* __restrict__ h0,
                                                     int nwaves) {
    const int lane = threadIdx.x & 63;
    const int wid = (blockIdx.x * 256 + threadIdx.x) >> 6;
    float wr[NF];  // lane holds column `lane` of W: W[k][lane], k=0..127
#pragma unroll
    for (int k = 0; k < NF; ++k) wr[k] = w[k * NH + lane];
    const float bias = b[lane];
    for (int n = wid; n < NN; n += nwaves) {
        float a0 = x[n * NF + lane];
        float a1 = x[n * NF + 64 + lane];
        float acc = bias;
#pragma unroll
        for (int k = 0; k < 64; ++k) acc = fmaf(__shfl(a0, k), wr[k], acc);
#pragma unroll
        for (int k = 0; k < 64; ++k) acc = fmaf(__shfl(a1, k), wr[64 + k], acc);
        h0[n * NH + lane] = __float2bfloat16(acc);
    }
}

// ---------------- conv: xw = 0.9 * relu(in) @ W ----------------
template <bool IN_BF16>
__global__ __launch_bounds__(256) void conv_kernel(const void* __restrict__ in_,
                                                   float* __restrict__ xw,
                                                   const float* __restrict__ w,
                                                   int nwaves) {
    const int lane = threadIdx.x & 63;
    const int wid = (blockIdx.x * 256 + threadIdx.x) >> 6;
    float wr[NH];
#pragma unroll
    for (int k = 0; k < NH; ++k) wr[k] = w[k * NH + lane];
    for (int n = wid; n < NN; n += nwaves) {
        float a;
        if constexpr (IN_BF16)
            a = __bfloat162float(((const __hip_bfloat16*)in_)[n * NH + lane]);
        else
            a = ((const float*)in_)[n * NH + lane];
        a = fmaxf(a, 0.0f);
        float s = 0.0f;
#pragma unroll
        for (int k = 0; k < 64; ++k) s = fmaf(__shfl(a, k), wr[k], s);
        xw[n * NH + lane] = 0.9f * s;
    }
}

// ------- SpMM CSR: acc[n] = 0.1*h0[n] + b + sum_e val*xw[col], wave per row -------
__global__ __launch_bounds__(256) void spmm_csr_kernel(const int* __restrict__ rs,
                                                       const int2* __restrict__ packed,
                                                       const float* __restrict__ xw,
                                                       const __hip_bfloat16* __restrict__ h0,
                                                       const float* __restrict__ b,
                                                       float* __restrict__ acc,
                                                       int nwaves) {
    const int lane = threadIdx.x & 63;
    const int wid = (blockIdx.x * 256 + threadIdx.x) >> 6;
    const float bias = b[lane];
    for (int n = wid; n < NN; n += nwaves) {
        const int s = rs[n];
        const int e2 = rs[n + 1];
        float a = fmaf(0.1f, __bfloat162float(h0[n * NH + lane]), bias);
        for (int base = s; base < e2; base += 64) {
            const int cnt = min(64, e2 - base);
            int2 ed = (lane < cnt) ? packed[base + lane] : make_int2(0, 0);
            for (int j = 0; j < cnt; ++j) {
                int c = __shfl(ed.x, j);
                float v = __int_as_float(__shfl(ed.y, j));
                a = fmaf(v, xw[c * NH + lane], a);
            }
        }
        acc[n * NH + lane] = a;
    }
}

// ---------------- fc1: out = relu(in) @ fc1_w + fc1_b ----------------
__global__ __launch_bounds__(256) void fc1_kernel(const float* __restrict__ in,
                                                  const float* __restrict__ w,
                                                  const float* __restrict__ b,
                                                  float* __restrict__ out,
                                                  int nwaves) {
    __shared__ float wl[NH * NC];  // 4 KB
    for (int i = threadIdx.x; i < NH * NC; i += 256) wl[i] = w[i];
    __syncthreads();
    const int lane = threadIdx.x & 63;
    const int wid = (blockIdx.x * 256 + threadIdx.x) >> 6;
    const int c = lane & 15;
    const int r = lane >> 4;
    const int src_base = lane & 48;  // r*16
    const float bias = b[c];
    for (int g = wid; g < NN / 4; g += nwaves) {
        int row = g * 4 + r;
        float a0 = fmaxf(in[row * NH + c], 0.0f);
        float a1 = fmaxf(in[row * NH + 16 + c], 0.0f);
        float a2 = fmaxf(in[row * NH + 32 + c], 0.0f);
        float a3 = fmaxf(in[row * NH + 48 + c], 0.0f);
        float s = bias;
#pragma unroll
        for (int k = 0; k < 16; ++k) s = fmaf(__shfl(a0, src_base + k), wl[k * NC + c], s);
#pragma unroll
        for (int k = 0; k < 16; ++k) s = fmaf(__shfl(a1, src_base + k), wl[(16 + k) * NC + c], s);
#pragma unroll
        for (int k = 0; k < 16; ++k) s = fmaf(__shfl(a2, src_base + k), wl[(32 + k) * NC + c], s);
#pragma unroll
        for (int k = 0; k < 16; ++k) s = fmaf(__shfl(a3, src_base + k), wl[(48 + k) * NC + c], s);
        out[row * NC + c] = s;
    }
}

extern "C" void kernel_launch(void* const* d_in, const int* in_sizes, int n_in,
                              void* d_out, int out_size, void* d_ws, size_t ws_size,
                              hipStream_t stream) {
    const float* x = (const float*)d_in[0];
    const int* rows = (const int*)d_in[1];
    const int* cols = (const int*)d_in[2];
    const float* vals = (const float*)d_in[3];
    const float* fc0_w = (const float*)d_in[4];
    const float* fc0_b = (const float*)d_in[5];
    const float* conv_w = (const float*)d_in[6];
    const float* conv_b = (const float*)d_in[7];
    const float* fc1_w = (const float*)d_in[8];
    const float* fc1_b = (const float*)d_in[9];
    float* out = (float*)d_out;

    // ---- workspace layout (74.8 MB; 8B-aligned sections) ----
    char* p = (char*)d_ws;
    __hip_bfloat16* h0 = (__hip_bfloat16*)p;          p += (size_t)NN * NH * 2;   // 12.8 MB
    float* acc = (float*)p;                           p += (size_t)NN * NH * 4;   // 25.6 MB
    float* xw = (float*)p;                            p += (size_t)NN * NH * 4;   // 25.6 MB
    int2* packed = (int2*)p;                          p += (size_t)NE * 8;        // 9.6 MB
    int* rs = (int*)p;                                p += (size_t)(NN + 1) * 4;
    int* cursor = (int*)p;                            p += (size_t)NN * 4;
    int* deg = (int*)p;                               p += (size_t)NN * 4;
    int* blk = (int*)p;                               p += 512 * 4;
    int* blk_off = (int*)p;                           p += 512 * 4;

    const int blocks = 2048;
    const int nwaves = blocks * 4;
    const int nthreads_e = 1200 * 256;

    // ---- CSR build (once; reused by all 4 layers) ----
    zero_deg_kernel<<<NB_SCAN, 256, 0, stream>>>(deg);
    hist_kernel<<<1200, 256, 0, stream>>>(rows, deg, nthreads_e);
    scan1_kernel<<<NB_SCAN, 256, 0, stream>>>(deg, rs, blk);
    scan2_kernel<<<1, 512, 0, stream>>>(blk, blk_off);
    scan3_kernel<<<NB_SCAN, 256, 0, stream>>>(rs, blk_off, cursor);
    scatter_kernel<<<1200, 256, 0, stream>>>(rows, cols, vals, cursor, packed, nthreads_e);

    // ---- dense + sparse pipeline ----
    fc0_kernel<<<blocks, 256, 0, stream>>>(x, fc0_w, fc0_b, h0, nwaves);

    // layer 1: conv reads bf16 h0; spmm writes acc. layers 2-4: conv reads fp32 acc.
    conv_kernel<true><<<blocks, 256, 0, stream>>>(h0, xw, conv_w + 0 * NH * NH, nwaves);
    spmm_csr_kernel<<<blocks, 256, 0, stream>>>(rs, packed, xw, h0, conv_b + 0 * NH, acc, nwaves);
    for (int i = 1; i < 4; ++i) {
        conv_kernel<false><<<blocks, 256, 0, stream>>>(acc, xw, conv_w + i * NH * NH, nwaves);
        spmm_csr_kernel<<<blocks, 256, 0, stream>>>(rs, packed, xw, h0, conv_b + i * NH, acc, nwaves);
    }

    fc1_kernel<<<1024, 256, 0, stream>>>(acc, fc1_w, fc1_b, out, 1024 * 4);
}

// Round 7
// 558.957 us; speedup vs baseline: 2.8095x; 1.7696x over previous
//
#include <hip/hip_runtime.h>
#include <hip/hip_bf16.h>

#define NN 100000
#define NE 1200000
#define NF 128
#define NH 64
#define NC 16
#define NB_SCAN 391   // ceil(NN/256)
#define TILE_R 64
#define NTILES 1563   // ceil(NN/64)

static __device__ __forceinline__ unsigned short f2bf(float f) {
    __hip_bfloat16 h = __float2bfloat16(f);
    return *reinterpret_cast<unsigned short*>(&h);
}
static __device__ __forceinline__ float bf2f(unsigned short u) {
    __hip_bfloat16 h = *reinterpret_cast<__hip_bfloat16*>(&u);
    return __bfloat162float(h);
}

// ---------------- CSR build ----------------
__global__ __launch_bounds__(256) void zero_deg_kernel(int* __restrict__ deg) {
    int i = blockIdx.x * 256 + threadIdx.x;
    if (i < NN) deg[i] = 0;
}

__global__ __launch_bounds__(256) void hist_kernel(const int* __restrict__ rows,
                                                   int* __restrict__ deg, int nthreads) {
    for (int e = blockIdx.x * 256 + threadIdx.x; e < NE; e += nthreads)
        atomicAdd(&deg[rows[e]], 1);
}

__global__ __launch_bounds__(256) void scan1_kernel(const int* __restrict__ deg,
                                                    int* __restrict__ rs,
                                                    int* __restrict__ blk) {
    __shared__ int sm[256];
    const int tid = threadIdx.x;
    const int i = blockIdx.x * 256 + tid;
    int v = (i < NN) ? deg[i] : 0;
    sm[tid] = v;
    __syncthreads();
#pragma unroll
    for (int off = 1; off < 256; off <<= 1) {
        int t = (tid >= off) ? sm[tid - off] : 0;
        __syncthreads();
        sm[tid] += t;
        __syncthreads();
    }
    if (i < NN) rs[i] = sm[tid] - v;
    if (tid == 255) blk[blockIdx.x] = sm[255];
}

__global__ __launch_bounds__(512) void scan2_kernel(const int* __restrict__ blk,
                                                    int* __restrict__ blk_off) {
    __shared__ int sm[512];
    const int tid = threadIdx.x;
    int v = (tid < NB_SCAN) ? blk[tid] : 0;
    sm[tid] = v;
    __syncthreads();
#pragma unroll
    for (int off = 1; off < 512; off <<= 1) {
        int t = (tid >= off) ? sm[tid - off] : 0;
        __syncthreads();
        sm[tid] += t;
        __syncthreads();
    }
    if (tid < NB_SCAN) blk_off[tid] = sm[tid] - v;
}

__global__ __launch_bounds__(256) void scan3_kernel(int* __restrict__ rs,
                                                    const int* __restrict__ blk_off,
                                                    int* __restrict__ cursor) {
    int i = blockIdx.x * 256 + threadIdx.x;
    if (i < NN) {
        int v = rs[i] + blk_off[i >> 8];
        rs[i] = v;
        cursor[i] = v;
    }
    if (i == 0) rs[NN] = NE;
}

__global__ __launch_bounds__(256) void scatter_kernel(const int* __restrict__ rows,
                                                      const int* __restrict__ cols,
                                                      const float* __restrict__ vals,
                                                      int* __restrict__ cursor,
                                                      int2* __restrict__ packed, int nthreads) {
    for (int e = blockIdx.x * 256 + threadIdx.x; e < NE; e += nthreads) {
        int r = rows[e];
        int pos = atomicAdd(&cursor[r], 1);
        packed[pos] = make_int2(cols[e], __float_as_int(vals[e]));
    }
}

// ------------- fc0: h0 = x @ fc0_w + b (pre-ReLU, bf16) -------------
// tile 64 rows; thread (c4=tid&15, r4g=tid>>4) owns rows r4g*4..+3 x cols c4*4..+3
__global__ __launch_bounds__(256) void fc0_kernel(const float* __restrict__ x,
                                                  const float* __restrict__ w,
                                                  const float* __restrict__ b,
                                                  unsigned short* __restrict__ h0) {
    __shared__ float Wl[NF * NH];       // 32 KB
    __shared__ float Xt[64 * TILE_R];   // 16 KB : Xt[k][row]
    const int tid = threadIdx.x;
    {
        const float4* w4 = (const float4*)w;
        float4* wl4 = (float4*)Wl;
#pragma unroll
        for (int i = tid; i < NF * NH / 4; i += 256) wl4[i] = w4[i];
    }
    const int n0 = blockIdx.x * TILE_R;
    const int c4 = tid & 15;
    const int r4g = tid >> 4;
    const float4 bias = *(const float4*)&b[c4 * 4];
    float acc[4][4];
#pragma unroll
    for (int i = 0; i < 4; ++i) {
        acc[i][0] = bias.x; acc[i][1] = bias.y; acc[i][2] = bias.z; acc[i][3] = bias.w;
    }
    const int lrow = tid & 63;
    const int qbase = tid >> 6;
    const int grow = min(n0 + lrow, NN - 1);
    for (int kk = 0; kk < NF; kk += 64) {
        __syncthreads();  // W ready (iter0) / Xt no longer read (iter1)
#pragma unroll
        for (int q = qbase; q < 16; q += 4) {
            float4 v = *(const float4*)&x[(size_t)grow * NF + kk + q * 4];
            Xt[(q * 4 + 0) * 64 + lrow] = v.x;
            Xt[(q * 4 + 1) * 64 + lrow] = v.y;
            Xt[(q * 4 + 2) * 64 + lrow] = v.z;
            Xt[(q * 4 + 3) * 64 + lrow] = v.w;
        }
        __syncthreads();
#pragma unroll 8
        for (int k = 0; k < 64; ++k) {
            float4 a4 = *(const float4*)&Xt[k * 64 + r4g * 4];
            float4 w4 = *(const float4*)&Wl[(kk + k) * NH + c4 * 4];
            acc[0][0] = fmaf(a4.x, w4.x, acc[0][0]); acc[0][1] = fmaf(a4.x, w4.y, acc[0][1]);
            acc[0][2] = fmaf(a4.x, w4.z, acc[0][2]); acc[0][3] = fmaf(a4.x, w4.w, acc[0][3]);
            acc[1][0] = fmaf(a4.y, w4.x, acc[1][0]); acc[1][1] = fmaf(a4.y, w4.y, acc[1][1]);
            acc[1][2] = fmaf(a4.y, w4.z, acc[1][2]); acc[1][3] = fmaf(a4.y, w4.w, acc[1][3]);
            acc[2][0] = fmaf(a4.z, w4.x, acc[2][0]); acc[2][1] = fmaf(a4.z, w4.y, acc[2][1]);
            acc[2][2] = fmaf(a4.z, w4.z, acc[2][2]); acc[2][3] = fmaf(a4.z, w4.w, acc[2][3]);
            acc[3][0] = fmaf(a4.w, w4.x, acc[3][0]); acc[3][1] = fmaf(a4.w, w4.y, acc[3][1]);
            acc[3][2] = fmaf(a4.w, w4.z, acc[3][2]); acc[3][3] = fmaf(a4.w, w4.w, acc[3][3]);
        }
    }
#pragma unroll
    for (int i = 0; i < 4; ++i) {
        int row = n0 + r4g * 4 + i;
        if (row < NN) {
            ushort4 o = { f2bf(acc[i][0]), f2bf(acc[i][1]), f2bf(acc[i][2]), f2bf(acc[i][3]) };
            *(ushort4*)&h0[(size_t)row * NH + c4 * 4] = o;
        }
    }
}

// ------------- conv: xw = 0.9 * relu(in) @ W  (K=64) -------------
template <bool IN_BF16>
__global__ __launch_bounds__(256) void conv_kernel(const void* __restrict__ in_,
                                                   float* __restrict__ xw,
                                                   const float* __restrict__ w) {
    __shared__ float Wl[NH * NH];       // 16 KB
    __shared__ float Xt[64 * TILE_R];   // 16 KB
    const int tid = threadIdx.x;
    {
        const float4* w4 = (const float4*)w;
        float4* wl4 = (float4*)Wl;
#pragma unroll
        for (int i = tid; i < NH * NH / 4; i += 256) wl4[i] = w4[i];
    }
    const int n0 = blockIdx.x * TILE_R;
    const int lrow = tid & 63;
    const int qbase = tid >> 6;
    const int grow = min(n0 + lrow, NN - 1);
#pragma unroll
    for (int q = qbase; q < 16; q += 4) {
        float e0, e1, e2, e3;
        if constexpr (IN_BF16) {
            ushort4 u = *(const ushort4*)&((const unsigned short*)in_)[(size_t)grow * NH + q * 4];
            e0 = bf2f(u.x); e1 = bf2f(u.y); e2 = bf2f(u.z); e3 = bf2f(u.w);
        } else {
            float4 v = *(const float4*)&((const float*)in_)[(size_t)grow * NH + q * 4];
            e0 = v.x; e1 = v.y; e2 = v.z; e3 = v.w;
        }
        Xt[(q * 4 + 0) * 64 + lrow] = fmaxf(e0, 0.0f);
        Xt[(q * 4 + 1) * 64 + lrow] = fmaxf(e1, 0.0f);
        Xt[(q * 4 + 2) * 64 + lrow] = fmaxf(e2, 0.0f);
        Xt[(q * 4 + 3) * 64 + lrow] = fmaxf(e3, 0.0f);
    }
    __syncthreads();
    const int c4 = tid & 15;
    const int r4g = tid >> 4;
    float acc[4][4];
#pragma unroll
    for (int i = 0; i < 4; ++i)
#pragma unroll
        for (int j = 0; j < 4; ++j) acc[i][j] = 0.0f;
#pragma unroll 8
    for (int k = 0; k < 64; ++k) {
        float4 a4 = *(const float4*)&Xt[k * 64 + r4g * 4];
        float4 w4 = *(const float4*)&Wl[k * NH + c4 * 4];
        acc[0][0] = fmaf(a4.x, w4.x, acc[0][0]); acc[0][1] = fmaf(a4.x, w4.y, acc[0][1]);
        acc[0][2] = fmaf(a4.x, w4.z, acc[0][2]); acc[0][3] = fmaf(a4.x, w4.w, acc[0][3]);
        acc[1][0] = fmaf(a4.y, w4.x, acc[1][0]); acc[1][1] = fmaf(a4.y, w4.y, acc[1][1]);
        acc[1][2] = fmaf(a4.y, w4.z, acc[1][2]); acc[1][3] = fmaf(a4.y, w4.w, acc[1][3]);
        acc[2][0] = fmaf(a4.z, w4.x, acc[2][0]); acc[2][1] = fmaf(a4.z, w4.y, acc[2][1]);
        acc[2][2] = fmaf(a4.z, w4.z, acc[2][2]); acc[2][3] = fmaf(a4.z, w4.w, acc[2][3]);
        acc[3][0] = fmaf(a4.w, w4.x, acc[3][0]); acc[3][1] = fmaf(a4.w, w4.y, acc[3][1]);
        acc[3][2] = fmaf(a4.w, w4.z, acc[3][2]); acc[3][3] = fmaf(a4.w, w4.w, acc[3][3]);
    }
#pragma unroll
    for (int i = 0; i < 4; ++i) {
        int row = n0 + r4g * 4 + i;
        if (row < NN) {
            float4 o = { 0.9f * acc[i][0], 0.9f * acc[i][1], 0.9f * acc[i][2], 0.9f * acc[i][3] };
            *(float4*)&xw[(size_t)row * NH + c4 * 4] = o;
        }
    }
}

// ------- SpMM CSR: acc[n] = 0.1*h0[n] + b + sum val*xw[col], wave/row, 4-way MLP -------
__global__ __launch_bounds__(256) void spmm_csr_kernel(const int* __restrict__ rs,
                                                       const int2* __restrict__ packed,
                                                       const float* __restrict__ xw,
                                                       const unsigned short* __restrict__ h0,
                                                       const float* __restrict__ b,
                                                       float* __restrict__ acc,
                                                       int nwaves) {
    const int lane = threadIdx.x & 63;
    const int wid = (blockIdx.x * 256 + threadIdx.x) >> 6;
    const float bias = b[lane];
    for (int n = wid; n < NN; n += nwaves) {
        const int s = rs[n];
        const int e2 = rs[n + 1];
        float a0 = fmaf(0.1f, bf2f(h0[(size_t)n * NH + lane]), bias);
        float a1 = 0.0f, a2 = 0.0f, a3 = 0.0f;
        for (int base = s; base < e2; base += 64) {
            const int cnt = min(64, e2 - base);
            int2 ed = (lane < cnt) ? packed[base + lane] : make_int2(0, 0);
            int j = 0;
            for (; j + 4 <= cnt; j += 4) {
                int c0 = __shfl(ed.x, j);
                int c1 = __shfl(ed.x, j + 1);
                int c2 = __shfl(ed.x, j + 2);
                int c3 = __shfl(ed.x, j + 3);
                float v0 = __int_as_float(__shfl(ed.y, j));
                float v1 = __int_as_float(__shfl(ed.y, j + 1));
                float v2 = __int_as_float(__shfl(ed.y, j + 2));
                float v3 = __int_as_float(__shfl(ed.y, j + 3));
                float g0 = xw[(size_t)c0 * NH + lane];
                float g1 = xw[(size_t)c1 * NH + lane];
                float g2 = xw[(size_t)c2 * NH + lane];
                float g3 = xw[(size_t)c3 * NH + lane];
                a0 = fmaf(v0, g0, a0);
                a1 = fmaf(v1, g1, a1);
                a2 = fmaf(v2, g2, a2);
                a3 = fmaf(v3, g3, a3);
            }
            for (; j < cnt; ++j) {
                int c = __shfl(ed.x, j);
                float v = __int_as_float(__shfl(ed.y, j));
                a0 = fmaf(v, xw[(size_t)c * NH + lane], a0);
            }
        }
        acc[(size_t)n * NH + lane] = (a0 + a1) + (a2 + a3);
    }
}

// ------------- fc1: out = relu(in) @ fc1_w + b -------------
__global__ __launch_bounds__(256) void fc1_kernel(const float* __restrict__ in,
                                                  const float* __restrict__ w,
                                                  const float* __restrict__ b,
                                                  float* __restrict__ out) {
    __shared__ float Wl[NH * NC];       // 4 KB
    __shared__ float Xt[64 * TILE_R];   // 16 KB
    const int tid = threadIdx.x;
    for (int i = tid; i < NH * NC; i += 256) Wl[i] = w[i];
    const int n0 = blockIdx.x * TILE_R;
    const int lrow = tid & 63;
    const int qbase = tid >> 6;
    const int grow = min(n0 + lrow, NN - 1);
#pragma unroll
    for (int q = qbase; q < 16; q += 4) {
        float4 v = *(const float4*)&in[(size_t)grow * NH + q * 4];
        Xt[(q * 4 + 0) * 64 + lrow] = fmaxf(v.x, 0.0f);
        Xt[(q * 4 + 1) * 64 + lrow] = fmaxf(v.y, 0.0f);
        Xt[(q * 4 + 2) * 64 + lrow] = fmaxf(v.z, 0.0f);
        Xt[(q * 4 + 3) * 64 + lrow] = fmaxf(v.w, 0.0f);
    }
    __syncthreads();
    const int c = tid & 15;
    const int r4g = tid >> 4;
    float a0 = b[c], a1 = b[c], a2 = b[c], a3 = b[c];
#pragma unroll 8
    for (int k = 0; k < 64; ++k) {
        float4 a4 = *(const float4*)&Xt[k * 64 + r4g * 4];
        float wv = Wl[k * NC + c];
        a0 = fmaf(a4.x, wv, a0);
        a1 = fmaf(a4.y, wv, a1);
        a2 = fmaf(a4.z, wv, a2);
        a3 = fmaf(a4.w, wv, a3);
    }
    int row = n0 + r4g * 4;
    if (row + 0 < NN) out[(size_t)(row + 0) * NC + c] = a0;
    if (row + 1 < NN) out[(size_t)(row + 1) * NC + c] = a1;
    if (row + 2 < NN) out[(size_t)(row + 2) * NC + c] = a2;
    if (row + 3 < NN) out[(size_t)(row + 3) * NC + c] = a3;
}

extern "C" void kernel_launch(void* const* d_in, const int* in_sizes, int n_in,
                              void* d_out, int out_size, void* d_ws, size_t ws_size,
                              hipStream_t stream) {
    const float* x = (const float*)d_in[0];
    const int* rows = (const int*)d_in[1];
    const int* cols = (const int*)d_in[2];
    const float* vals = (const float*)d_in[3];
    const float* fc0_w = (const float*)d_in[4];
    const float* fc0_b = (const float*)d_in[5];
    const float* conv_w = (const float*)d_in[6];
    const float* conv_b = (const float*)d_in[7];
    const float* fc1_w = (const float*)d_in[8];
    const float* fc1_b = (const float*)d_in[9];
    float* out = (float*)d_out;

    char* p = (char*)d_ws;
    unsigned short* h0 = (unsigned short*)p;          p += (size_t)NN * NH * 2;   // 12.8 MB
    float* acc = (float*)p;                           p += (size_t)NN * NH * 4;   // 25.6 MB
    float* xw = (float*)p;                            p += (size_t)NN * NH * 4;   // 25.6 MB
    int2* packed = (int2*)p;                          p += (size_t)NE * 8;        // 9.6 MB
    int* rs = (int*)p;                                p += (size_t)(NN + 1) * 4;
    int* cursor = (int*)p;                            p += (size_t)NN * 4;
    int* deg = (int*)p;                               p += (size_t)NN * 4;
    int* blk = (int*)p;                               p += 512 * 4;
    int* blk_off = (int*)p;                           p += 512 * 4;

    const int nthreads_e = 1200 * 256;
    const int sblocks = 2048;
    const int snwaves = sblocks * 4;

    // ---- CSR build (reused by all 4 layers) ----
    zero_deg_kernel<<<NB_SCAN, 256, 0, stream>>>(deg);
    hist_kernel<<<1200, 256, 0, stream>>>(rows, deg, nthreads_e);
    scan1_kernel<<<NB_SCAN, 256, 0, stream>>>(deg, rs, blk);
    scan2_kernel<<<1, 512, 0, stream>>>(blk, blk_off);
    scan3_kernel<<<NB_SCAN, 256, 0, stream>>>(rs, blk_off, cursor);
    scatter_kernel<<<1200, 256, 0, stream>>>(rows, cols, vals, cursor, packed, nthreads_e);

    // ---- dense + sparse pipeline ----
    fc0_kernel<<<NTILES, 256, 0, stream>>>(x, fc0_w, fc0_b, h0);

    conv_kernel<true><<<NTILES, 256, 0, stream>>>(h0, xw, conv_w + 0 * NH * NH);
    spmm_csr_kernel<<<sblocks, 256, 0, stream>>>(rs, packed, xw, h0, conv_b + 0 * NH, acc, snwaves);
    for (int i = 1; i < 4; ++i) {
        conv_kernel<false><<<NTILES, 256, 0, stream>>>(acc, xw, conv_w + i * NH * NH);
        spmm_csr_kernel<<<sblocks, 256, 0, stream>>>(rs, packed, xw, h0, conv_b + i * NH, acc, snwaves);
    }

    fc1_kernel<<<NTILES, 256, 0, stream>>>(acc, fc1_w, fc1_b, out);
}

// Round 8
// 479.663 us; speedup vs baseline: 3.2739x; 1.1653x over previous
//
#include <hip/hip_runtime.h>
#include <hip/hip_bf16.h>

#define NN 100000
#define NE 1200000
#define NF 128
#define NH 64
#define NC 16
#define NB_SCAN 391   // ceil(NN/256)
#define TILE_R 64
#define NTILES 1563   // ceil(NN/64)

static __device__ __forceinline__ unsigned short f2bf(float f) {
    __hip_bfloat16 h = __float2bfloat16(f);
    return *reinterpret_cast<unsigned short*>(&h);
}
static __device__ __forceinline__ float bf2f(unsigned short u) {
    __hip_bfloat16 h = *reinterpret_cast<__hip_bfloat16*>(&u);
    return __bfloat162float(h);
}

// ---------------- CSR build ----------------
__global__ __launch_bounds__(256) void zero_deg_kernel(int* __restrict__ deg) {
    int i = blockIdx.x * 256 + threadIdx.x;
    if (i < NN) deg[i] = 0;
}

// XCD-affinity histogram: cohort (blockIdx&7) handles rows with ((r>>9)&7)==cohort.
// All atomics on a 512-row band come from one XCD -> L2-local RMW.
__global__ __launch_bounds__(256) void hist_kernel(const int* __restrict__ rows,
                                                   int* __restrict__ deg, int cohort_threads) {
    const int xcd = blockIdx.x & 7;
    const int ctid = (blockIdx.x >> 3) * 256 + threadIdx.x;
    for (int e = ctid; e < NE; e += cohort_threads) {
        int r = rows[e];
        if (((r >> 9) & 7) == xcd) atomicAdd(&deg[r], 1);
    }
}

__global__ __launch_bounds__(256) void scan1_kernel(const int* __restrict__ deg,
                                                    int* __restrict__ rs,
                                                    int* __restrict__ blk) {
    __shared__ int sm[256];
    const int tid = threadIdx.x;
    const int i = blockIdx.x * 256 + tid;
    int v = (i < NN) ? deg[i] : 0;
    sm[tid] = v;
    __syncthreads();
#pragma unroll
    for (int off = 1; off < 256; off <<= 1) {
        int t = (tid >= off) ? sm[tid - off] : 0;
        __syncthreads();
        sm[tid] += t;
        __syncthreads();
    }
    if (i < NN) rs[i] = sm[tid] - v;
    if (tid == 255) blk[blockIdx.x] = sm[255];
}

__global__ __launch_bounds__(512) void scan2_kernel(const int* __restrict__ blk,
                                                    int* __restrict__ blk_off) {
    __shared__ int sm[512];
    const int tid = threadIdx.x;
    int v = (tid < NB_SCAN) ? blk[tid] : 0;
    sm[tid] = v;
    __syncthreads();
#pragma unroll
    for (int off = 1; off < 512; off <<= 1) {
        int t = (tid >= off) ? sm[tid - off] : 0;
        __syncthreads();
        sm[tid] += t;
        __syncthreads();
    }
    if (tid < NB_SCAN) blk_off[tid] = sm[tid] - v;
}

__global__ __launch_bounds__(256) void scan3_kernel(int* __restrict__ rs,
                                                    const int* __restrict__ blk_off,
                                                    int* __restrict__ cursor) {
    int i = blockIdx.x * 256 + threadIdx.x;
    if (i < NN) {
        int v = rs[i] + blk_off[i >> 8];
        rs[i] = v;
        cursor[i] = v;
    }
    if (i == 0) rs[NN] = NE;
}

// XCD-affinity scatter: same cohort filter -> packed-region writes for a band
// all come from one XCD; lines merge in its L2 before eviction.
__global__ __launch_bounds__(256) void scatter_kernel(const int* __restrict__ rows,
                                                      const int* __restrict__ cols,
                                                      const float* __restrict__ vals,
                                                      int* __restrict__ cursor,
                                                      int2* __restrict__ packed, int cohort_threads) {
    const int xcd = blockIdx.x & 7;
    const int ctid = (blockIdx.x >> 3) * 256 + threadIdx.x;
    for (int e = ctid; e < NE; e += cohort_threads) {
        int r = rows[e];
        if (((r >> 9) & 7) == xcd) {
            int pos = atomicAdd(&cursor[r], 1);
            packed[pos] = make_int2(cols[e], __float_as_int(vals[e]));
        }
    }
}

// ------------- fc0: h0 = x @ fc0_w + b (pre-ReLU, bf16) -------------
__global__ __launch_bounds__(256) void fc0_kernel(const float* __restrict__ x,
                                                  const float* __restrict__ w,
                                                  const float* __restrict__ b,
                                                  unsigned short* __restrict__ h0) {
    __shared__ float Wl[NF * NH];       // 32 KB
    __shared__ float Xt[64 * TILE_R];   // 16 KB : Xt[k][row]
    const int tid = threadIdx.x;
    {
        const float4* w4 = (const float4*)w;
        float4* wl4 = (float4*)Wl;
#pragma unroll
        for (int i = tid; i < NF * NH / 4; i += 256) wl4[i] = w4[i];
    }
    const int n0 = blockIdx.x * TILE_R;
    const int c4 = tid & 15;
    const int r4g = tid >> 4;
    const float4 bias = *(const float4*)&b[c4 * 4];
    float acc[4][4];
#pragma unroll
    for (int i = 0; i < 4; ++i) {
        acc[i][0] = bias.x; acc[i][1] = bias.y; acc[i][2] = bias.z; acc[i][3] = bias.w;
    }
    const int lrow = tid & 63;
    const int qbase = tid >> 6;
    const int grow = min(n0 + lrow, NN - 1);
    for (int kk = 0; kk < NF; kk += 64) {
        __syncthreads();
#pragma unroll
        for (int q = qbase; q < 16; q += 4) {
            float4 v = *(const float4*)&x[(size_t)grow * NF + kk + q * 4];
            Xt[(q * 4 + 0) * 64 + lrow] = v.x;
            Xt[(q * 4 + 1) * 64 + lrow] = v.y;
            Xt[(q * 4 + 2) * 64 + lrow] = v.z;
            Xt[(q * 4 + 3) * 64 + lrow] = v.w;
        }
        __syncthreads();
#pragma unroll 8
        for (int k = 0; k < 64; ++k) {
            float4 a4 = *(const float4*)&Xt[k * 64 + r4g * 4];
            float4 w4 = *(const float4*)&Wl[(kk + k) * NH + c4 * 4];
            acc[0][0] = fmaf(a4.x, w4.x, acc[0][0]); acc[0][1] = fmaf(a4.x, w4.y, acc[0][1]);
            acc[0][2] = fmaf(a4.x, w4.z, acc[0][2]); acc[0][3] = fmaf(a4.x, w4.w, acc[0][3]);
            acc[1][0] = fmaf(a4.y, w4.x, acc[1][0]); acc[1][1] = fmaf(a4.y, w4.y, acc[1][1]);
            acc[1][2] = fmaf(a4.y, w4.z, acc[1][2]); acc[1][3] = fmaf(a4.y, w4.w, acc[1][3]);
            acc[2][0] = fmaf(a4.z, w4.x, acc[2][0]); acc[2][1] = fmaf(a4.z, w4.y, acc[2][1]);
            acc[2][2] = fmaf(a4.z, w4.z, acc[2][2]); acc[2][3] = fmaf(a4.z, w4.w, acc[2][3]);
            acc[3][0] = fmaf(a4.w, w4.x, acc[3][0]); acc[3][1] = fmaf(a4.w, w4.y, acc[3][1]);
            acc[3][2] = fmaf(a4.w, w4.z, acc[3][2]); acc[3][3] = fmaf(a4.w, w4.w, acc[3][3]);
        }
    }
#pragma unroll
    for (int i = 0; i < 4; ++i) {
        int row = n0 + r4g * 4 + i;
        if (row < NN) {
            ushort4 o = { f2bf(acc[i][0]), f2bf(acc[i][1]), f2bf(acc[i][2]), f2bf(acc[i][3]) };
            *(ushort4*)&h0[(size_t)row * NH + c4 * 4] = o;
        }
    }
}

// ------------- conv: xw = 0.9 * relu(in) @ W  (K=64), OUTPUT bf16 -------------
template <bool IN_BF16>
__global__ __launch_bounds__(256) void conv_kernel(const void* __restrict__ in_,
                                                   unsigned short* __restrict__ xw,
                                                   const float* __restrict__ w) {
    __shared__ float Wl[NH * NH];       // 16 KB
    __shared__ float Xt[64 * TILE_R];   // 16 KB
    const int tid = threadIdx.x;
    {
        const float4* w4 = (const float4*)w;
        float4* wl4 = (float4*)Wl;
#pragma unroll
        for (int i = tid; i < NH * NH / 4; i += 256) wl4[i] = w4[i];
    }
    const int n0 = blockIdx.x * TILE_R;
    const int lrow = tid & 63;
    const int qbase = tid >> 6;
    const int grow = min(n0 + lrow, NN - 1);
#pragma unroll
    for (int q = qbase; q < 16; q += 4) {
        float e0, e1, e2, e3;
        if constexpr (IN_BF16) {
            ushort4 u = *(const ushort4*)&((const unsigned short*)in_)[(size_t)grow * NH + q * 4];
            e0 = bf2f(u.x); e1 = bf2f(u.y); e2 = bf2f(u.z); e3 = bf2f(u.w);
        } else {
            float4 v = *(const float4*)&((const float*)in_)[(size_t)grow * NH + q * 4];
            e0 = v.x; e1 = v.y; e2 = v.z; e3 = v.w;
        }
        Xt[(q * 4 + 0) * 64 + lrow] = fmaxf(e0, 0.0f);
        Xt[(q * 4 + 1) * 64 + lrow] = fmaxf(e1, 0.0f);
        Xt[(q * 4 + 2) * 64 + lrow] = fmaxf(e2, 0.0f);
        Xt[(q * 4 + 3) * 64 + lrow] = fmaxf(e3, 0.0f);
    }
    __syncthreads();
    const int c4 = tid & 15;
    const int r4g = tid >> 4;
    float acc[4][4];
#pragma unroll
    for (int i = 0; i < 4; ++i)
#pragma unroll
        for (int j = 0; j < 4; ++j) acc[i][j] = 0.0f;
#pragma unroll 8
    for (int k = 0; k < 64; ++k) {
        float4 a4 = *(const float4*)&Xt[k * 64 + r4g * 4];
        float4 w4 = *(const float4*)&Wl[k * NH + c4 * 4];
        acc[0][0] = fmaf(a4.x, w4.x, acc[0][0]); acc[0][1] = fmaf(a4.x, w4.y, acc[0][1]);
        acc[0][2] = fmaf(a4.x, w4.z, acc[0][2]); acc[0][3] = fmaf(a4.x, w4.w, acc[0][3]);
        acc[1][0] = fmaf(a4.y, w4.x, acc[1][0]); acc[1][1] = fmaf(a4.y, w4.y, acc[1][1]);
        acc[1][2] = fmaf(a4.y, w4.z, acc[1][2]); acc[1][3] = fmaf(a4.y, w4.w, acc[1][3]);
        acc[2][0] = fmaf(a4.z, w4.x, acc[2][0]); acc[2][1] = fmaf(a4.z, w4.y, acc[2][1]);
        acc[2][2] = fmaf(a4.z, w4.z, acc[2][2]); acc[2][3] = fmaf(a4.z, w4.w, acc[2][3]);
        acc[3][0] = fmaf(a4.w, w4.x, acc[3][0]); acc[3][1] = fmaf(a4.w, w4.y, acc[3][1]);
        acc[3][2] = fmaf(a4.w, w4.z, acc[3][2]); acc[3][3] = fmaf(a4.w, w4.w, acc[3][3]);
    }
#pragma unroll
    for (int i = 0; i < 4; ++i) {
        int row = n0 + r4g * 4 + i;
        if (row < NN) {
            ushort4 o = { f2bf(0.9f * acc[i][0]), f2bf(0.9f * acc[i][1]),
                          f2bf(0.9f * acc[i][2]), f2bf(0.9f * acc[i][3]) };
            *(ushort4*)&xw[(size_t)row * NH + c4 * 4] = o;
        }
    }
}

// ------- SpMM CSR: acc[n] = 0.1*h0[n] + b + sum val*xw[col], wave/row, bf16 gathers -------
__global__ __launch_bounds__(256) void spmm_csr_kernel(const int* __restrict__ rs,
                                                       const int2* __restrict__ packed,
                                                       const unsigned short* __restrict__ xw,
                                                       const unsigned short* __restrict__ h0,
                                                       const float* __restrict__ b,
                                                       float* __restrict__ acc,
                                                       int nwaves) {
    const int lane = threadIdx.x & 63;
    const int wid = (blockIdx.x * 256 + threadIdx.x) >> 6;
    const float bias = b[lane];
    for (int n = wid; n < NN; n += nwaves) {
        const int s = rs[n];
        const int e2 = rs[n + 1];
        float a0 = fmaf(0.1f, bf2f(h0[(size_t)n * NH + lane]), bias);
        float a1 = 0.0f, a2 = 0.0f, a3 = 0.0f;
        for (int base = s; base < e2; base += 64) {
            const int cnt = min(64, e2 - base);
            int2 ed = (lane < cnt) ? packed[base + lane] : make_int2(0, 0);
            int j = 0;
            for (; j + 4 <= cnt; j += 4) {
                int c0 = __shfl(ed.x, j);
                int c1 = __shfl(ed.x, j + 1);
                int c2 = __shfl(ed.x, j + 2);
                int c3 = __shfl(ed.x, j + 3);
                float v0 = __int_as_float(__shfl(ed.y, j));
                float v1 = __int_as_float(__shfl(ed.y, j + 1));
                float v2 = __int_as_float(__shfl(ed.y, j + 2));
                float v3 = __int_as_float(__shfl(ed.y, j + 3));
                float g0 = bf2f(xw[(size_t)c0 * NH + lane]);
                float g1 = bf2f(xw[(size_t)c1 * NH + lane]);
                float g2 = bf2f(xw[(size_t)c2 * NH + lane]);
                float g3 = bf2f(xw[(size_t)c3 * NH + lane]);
                a0 = fmaf(v0, g0, a0);
                a1 = fmaf(v1, g1, a1);
                a2 = fmaf(v2, g2, a2);
                a3 = fmaf(v3, g3, a3);
            }
            for (; j < cnt; ++j) {
                int c = __shfl(ed.x, j);
                float v = __int_as_float(__shfl(ed.y, j));
                a0 = fmaf(v, bf2f(xw[(size_t)c * NH + lane]), a0);
            }
        }
        acc[(size_t)n * NH + lane] = (a0 + a1) + (a2 + a3);
    }
}

// ------------- fc1: out = relu(in) @ fc1_w + b -------------
__global__ __launch_bounds__(256) void fc1_kernel(const float* __restrict__ in,
                                                  const float* __restrict__ w,
                                                  const float* __restrict__ b,
                                                  float* __restrict__ out) {
    __shared__ float Wl[NH * NC];       // 4 KB
    __shared__ float Xt[64 * TILE_R];   // 16 KB
    const int tid = threadIdx.x;
    for (int i = tid; i < NH * NC; i += 256) Wl[i] = w[i];
    const int n0 = blockIdx.x * TILE_R;
    const int lrow = tid & 63;
    const int qbase = tid >> 6;
    const int grow = min(n0 + lrow, NN - 1);
#pragma unroll
    for (int q = qbase; q < 16; q += 4) {
        float4 v = *(const float4*)&in[(size_t)grow * NH + q * 4];
        Xt[(q * 4 + 0) * 64 + lrow] = fmaxf(v.x, 0.0f);
        Xt[(q * 4 + 1) * 64 + lrow] = fmaxf(v.y, 0.0f);
        Xt[(q * 4 + 2) * 64 + lrow] = fmaxf(v.z, 0.0f);
        Xt[(q * 4 + 3) * 64 + lrow] = fmaxf(v.w, 0.0f);
    }
    __syncthreads();
    const int c = tid & 15;
    const int r4g = tid >> 4;
    float a0 = b[c], a1 = b[c], a2 = b[c], a3 = b[c];
#pragma unroll 8
    for (int k = 0; k < 64; ++k) {
        float4 a4 = *(const float4*)&Xt[k * 64 + r4g * 4];
        float wv = Wl[k * NC + c];
        a0 = fmaf(a4.x, wv, a0);
        a1 = fmaf(a4.y, wv, a1);
        a2 = fmaf(a4.z, wv, a2);
        a3 = fmaf(a4.w, wv, a3);
    }
    int row = n0 + r4g * 4;
    if (row + 0 < NN) out[(size_t)(row + 0) * NC + c] = a0;
    if (row + 1 < NN) out[(size_t)(row + 1) * NC + c] = a1;
    if (row + 2 < NN) out[(size_t)(row + 2) * NC + c] = a2;
    if (row + 3 < NN) out[(size_t)(row + 3) * NC + c] = a3;
}

extern "C" void kernel_launch(void* const* d_in, const int* in_sizes, int n_in,
                              void* d_out, int out_size, void* d_ws, size_t ws_size,
                              hipStream_t stream) {
    const float* x = (const float*)d_in[0];
    const int* rows = (const int*)d_in[1];
    const int* cols = (const int*)d_in[2];
    const float* vals = (const float*)d_in[3];
    const float* fc0_w = (const float*)d_in[4];
    const float* fc0_b = (const float*)d_in[5];
    const float* conv_w = (const float*)d_in[6];
    const float* conv_b = (const float*)d_in[7];
    const float* fc1_w = (const float*)d_in[8];
    const float* fc1_b = (const float*)d_in[9];
    float* out = (float*)d_out;

    char* p = (char*)d_ws;
    unsigned short* h0 = (unsigned short*)p;          p += (size_t)NN * NH * 2;   // 12.8 MB
    float* acc = (float*)p;                           p += (size_t)NN * NH * 4;   // 25.6 MB
    unsigned short* xw = (unsigned short*)p;          p += (size_t)NN * NH * 2;   // 12.8 MB
    int2* packed = (int2*)p;                          p += (size_t)NE * 8;        // 9.6 MB
    int* rs = (int*)p;                                p += (size_t)(NN + 1) * 4;
    int* cursor = (int*)p;                            p += (size_t)NN * 4;
    int* deg = (int*)p;                               p += (size_t)NN * 4;
    int* blk = (int*)p;                               p += 512 * 4;
    int* blk_off = (int*)p;                           p += 512 * 4;

    const int ebl = 1200;                 // edge-kernel blocks (divisible by 8)
    const int cohort_threads = (ebl / 8) * 256;
    const int sblocks = 2048;
    const int snwaves = sblocks * 4;

    // ---- CSR build (reused by all 4 layers) ----
    zero_deg_kernel<<<NB_SCAN, 256, 0, stream>>>(deg);
    hist_kernel<<<ebl, 256, 0, stream>>>(rows, deg, cohort_threads);
    scan1_kernel<<<NB_SCAN, 256, 0, stream>>>(deg, rs, blk);
    scan2_kernel<<<1, 512, 0, stream>>>(blk, blk_off);
    scan3_kernel<<<NB_SCAN, 256, 0, stream>>>(rs, blk_off, cursor);
    scatter_kernel<<<ebl, 256, 0, stream>>>(rows, cols, vals, cursor, packed, cohort_threads);

    // ---- dense + sparse pipeline ----
    fc0_kernel<<<NTILES, 256, 0, stream>>>(x, fc0_w, fc0_b, h0);

    conv_kernel<true><<<NTILES, 256, 0, stream>>>(h0, xw, conv_w + 0 * NH * NH);
    spmm_csr_kernel<<<sblocks, 256, 0, stream>>>(rs, packed, xw, h0, conv_b + 0 * NH, acc, snwaves);
    for (int i = 1; i < 4; ++i) {
        conv_kernel<false><<<NTILES, 256, 0, stream>>>(acc, xw, conv_w + i * NH * NH);
        spmm_csr_kernel<<<sblocks, 256, 0, stream>>>(rs, packed, xw, h0, conv_b + i * NH, acc, snwaves);
    }

    fc1_kernel<<<NTILES, 256, 0, stream>>>(acc, fc1_w, fc1_b, out);
}